// Round 7
// baseline (204.369 us; speedup 1.0000x reference)
//
#include <hip/hip_runtime.h>
#include <cstdint>

// BatchInvariantAttention: B=4 H=16 S=2048 D=64, fp32 in/out, full softmax attention.
// v8 = v7 (64 q rows/wave, 1 barrier/chunk, in-register P, MFMA row-sum) with the
// V-tile swizzle replaced by a bank-minimal slot swizzle:
//   element (d, kv) lives at  vb[d*64 + 4*((kv>>2) ^ (d&15))]  (+ kv&3)
// Analysis (enumerated): staging V-writes, and V b64 reads, are now EXACTLY at the
// b64 4-cycle bank minimum (v7's (vkm>>3)^(d&7) granule swizzle confined each write
// instruction's 64 lanes to 2 x 32B windows -> the 11.5M conflict cycles).
// Also: V fragments hoisted above the exp phase (DS latency under VALU, v6-proven).
// K path unchanged (analytically at minimum already).

#define S_LEN 2048
#define D_DIM 64
#define BN 64
#define NCHUNK (S_LEN / BN)
#define BH 64

typedef __attribute__((ext_vector_type(8))) short bf16x8;
typedef __attribute__((ext_vector_type(4))) float f32x4;
typedef __attribute__((ext_vector_type(2))) unsigned int u32x2;

static __device__ __forceinline__ float fast_exp2(float x) {
#if __has_builtin(__builtin_amdgcn_exp2f)
    return __builtin_amdgcn_exp2f(x);
#else
    float r;
    asm volatile("v_exp_f32 %0, %1" : "=v"(r) : "v"(x));
    return r;
#endif
}

static __device__ __forceinline__ float fast_rcp(float x) {
#if __has_builtin(__builtin_amdgcn_rcpf)
    return __builtin_amdgcn_rcpf(x);
#else
    return 1.0f / x;
#endif
}

// single-instruction packed cvt (RNE). dst.lo = bf16(a), dst.hi = bf16(b)
static __device__ __forceinline__ unsigned int cvt_pk_bf16(float a, float b) {
    unsigned int r;
    asm("v_cvt_pk_bf16_f32 %0, %1, %2" : "=v"(r) : "v"(a), "v"(b));
    return r;
}

__global__ __launch_bounds__(256, 2)
void attn_fwd(const float* __restrict__ Qg, const float* __restrict__ Kg,
              const float* __restrict__ Vg, float* __restrict__ Og) {
    const int bh   = blockIdx.x;   // 0..63 (fastest -> XCD = bh%8; same-bh blocks share XCD)
    const int tile = blockIdx.y;   // 0..7
    const int tid  = threadIdx.x;
    const int wave = tid >> 6;
    const int lane = tid & 63;
    const int quad = lane >> 4;
    const int lc   = lane & 15;

    const size_t base = (size_t)bh * S_LEN * D_DIM;
    const float* Q = Qg + base;
    const float* K = Kg + base;
    const float* V = Vg + base;
    float*       O = Og + base;

    const int q0 = tile * 256 + wave * 64;   // this wave's 64 q rows

    __shared__ __align__(16) short Kb[2][64 * 64];   // [kv][d], granule ^ (kv&7) swizzle
    __shared__ __align__(16) short Vt[2][64 * 64];   // [d][kv], slot = (kv>>2)^(d&15)
    // 32768 B total

    // ---- Q fragments (B-operand: n=lc=q, k slots = quad*8+j), scale = log2(e)/8 folded in
    const float QSCALE = 1.44269504088896f / 8.0f;
    bf16x8 qf[4][2];
#pragma unroll
    for (int qb = 0; qb < 4; ++qb)
#pragma unroll
        for (int dc = 0; dc < 2; ++dc) {
            const float* src = Q + (size_t)(q0 + qb * 16 + lc) * D_DIM + dc * 32 + quad * 8;
            f32x4 a = *(const f32x4*)src;
            f32x4 b = *(const f32x4*)(src + 4);
            union { unsigned int u[4]; bf16x8 v; } cvt;
            cvt.u[0] = cvt_pk_bf16(a[0] * QSCALE, a[1] * QSCALE);
            cvt.u[1] = cvt_pk_bf16(a[2] * QSCALE, a[3] * QSCALE);
            cvt.u[2] = cvt_pk_bf16(b[0] * QSCALE, b[1] * QSCALE);
            cvt.u[3] = cvt_pk_bf16(b[2] * QSCALE, b[3] * QSCALE);
            qf[qb][dc] = cvt.v;
        }

    // all-ones bf16 B-fragment for the row-sum MFMA
    bf16x8 ones;
    {
        union { unsigned int u[4]; bf16x8 v; } cv;
#pragma unroll
        for (int i = 0; i < 4; ++i) cv.u[i] = 0x3F803F80u;
        ones = cv.v;
    }

    f32x4 oacc[4][4];   // [qb][dblk]  O accumulators (C layout: row=q=quad*4+r, col=d=lc)
    f32x4 lacc[4];      // [qb]        row-sum accumulators (same row layout)
#pragma unroll
    for (int qb = 0; qb < 4; ++qb) {
        lacc[qb] = (f32x4){0.f, 0.f, 0.f, 0.f};
#pragma unroll
        for (int dblk = 0; dblk < 4; ++dblk)
            oacc[qb][dblk] = (f32x4){0.f, 0.f, 0.f, 0.f};
    }

    // staging addressing (each thread stages 4 K row-quarters + a 4x4 V micro-tile)
    const int krow = tid >> 4;           // 0..15
    const int kcol = (tid & 15) * 4;     // d offset 0,4,..,60
    const int gk   = kcol >> 3;          // 16B granule of kcol
    const int vkm  = (tid >> 4) * 4;     // kv micro-base for V transpose
    const int vu   = vkm >> 2;           // kv slot index (0..15)
    const float* kptr = K + (size_t)krow * D_DIM + kcol;
    const float* vptr = V + (size_t)vkm * D_DIM + kcol;

    // prologue: chunk 0 globals in flight
    f32x4 kreg[4], vreg[4];
#pragma unroll
    for (int i = 0; i < 4; ++i) kreg[i] = *(const f32x4*)(kptr + (size_t)i * 16 * D_DIM);
#pragma unroll
    for (int i = 0; i < 4; ++i) vreg[i] = *(const f32x4*)(vptr + (size_t)i * D_DIM);
    kptr += BN * D_DIM;
    vptr += BN * D_DIM;

#pragma unroll 1
    for (int ch = 0; ch < NCHUNK; ++ch) {
        short* kb = Kb[ch & 1];
        short* vb = Vt[ch & 1];

        // ---- publish this chunk (WAR-safe with 1 barrier: readers of buf[ch&1]
        // finished before the previous barrier)
#pragma unroll
        for (int i = 0; i < 4; ++i) {
            const int row = krow + i * 16;
            u32x2 w;
            w[0] = cvt_pk_bf16(kreg[i][0], kreg[i][1]);
            w[1] = cvt_pk_bf16(kreg[i][2], kreg[i][3]);
            *(u32x2*)(&kb[row * 64 + ((gk ^ (row & 7)) << 3) + (kcol & 7)]) = w;
        }
#pragma unroll
        for (int j = 0; j < 4; ++j) {   // 4x4 in-register transpose of V micro-tile
            const int d = kcol + j;
            u32x2 w;
            w[0] = cvt_pk_bf16(vreg[0][j], vreg[1][j]);   // kv = vkm+0, vkm+1
            w[1] = cvt_pk_bf16(vreg[2][j], vreg[3][j]);   // kv = vkm+2, vkm+3
            *(u32x2*)(&vb[d * 64 + 4 * (vu ^ (d & 15))]) = w;
        }

        // ---- prefetch next chunk's globals (in flight across barrier + compute)
        if (ch + 1 < NCHUNK) {
#pragma unroll
            for (int i = 0; i < 4; ++i) kreg[i] = *(const f32x4*)(kptr + (size_t)i * 16 * D_DIM);
#pragma unroll
            for (int i = 0; i < 4; ++i) vreg[i] = *(const f32x4*)(vptr + (size_t)i * D_DIM);
            kptr += BN * D_DIM;
            vptr += BN * D_DIM;
        }

        __syncthreads();   // tiles visible to all waves (one barrier per chunk)

        // ---- S^T = K_tile . Q^T : C frag lane holds q=lc, kv = kvf*16 + quad*4 + r
        f32x4 st[4][4];    // [qb][kvf]
        __builtin_amdgcn_s_setprio(1);
#pragma unroll
        for (int kvf = 0; kvf < 4; ++kvf) {
            const int krr = kvf * 16 + lc;
            const bf16x8 ka  = *(const bf16x8*)(&kb[krr * 64 + ((quad       ^ (lc & 7)) << 3)]);
            const bf16x8 kb2 = *(const bf16x8*)(&kb[krr * 64 + (((quad + 4) ^ (lc & 7)) << 3)]);
#pragma unroll
            for (int qb = 0; qb < 4; ++qb) {
                f32x4 c = {0.f, 0.f, 0.f, 0.f};
                c = __builtin_amdgcn_mfma_f32_16x16x32_bf16(ka,  qf[qb][0], c, 0, 0, 0);
                c = __builtin_amdgcn_mfma_f32_16x16x32_bf16(kb2, qf[qb][1], c, 0, 0, 0);
                st[qb][kvf] = c;
            }
        }
        __builtin_amdgcn_s_setprio(0);

        // ---- V fragments hoisted: B-frag slot j = V[kv=32m+16(j>>2)+4t+(j&3)][d]
        //   q[0] <- slot (8m+quad)^(d&15), q[1] <- slot (8m+4+quad)^(d&15)
        // (DS latency hides under the exp/cvt phase below)
        bf16x8 vfm[2][4];
#pragma unroll
        for (int m = 0; m < 2; ++m)
#pragma unroll
            for (int dblk = 0; dblk < 4; ++dblk) {
                const int d = dblk * 16 + lc;
                union { unsigned long long q[2]; bf16x8 v; } uv;
                uv.q[0] = *(const unsigned long long*)(&vb[d * 64 + 4 * ((8 * m + quad)     ^ (d & 15))]);
                uv.q[1] = *(const unsigned long long*)(&vb[d * 64 + 4 * ((8 * m + 4 + quad) ^ (d & 15))]);
                vfm[m][dblk] = uv.v;
            }

        // ---- p = exp2(s); PV A-frags built IN REGISTERS (HW-proven layout).
        // Lane (q=lc, quad t) holds P[q][kv=16kvf+4t+r]. Slot j of pf[qb][m] is
        // st[qb][2m+(j>>2)][j&3]  ->  kv = 32m + 16(j>>2) + 4t + (j&3).
        bf16x8 pf[4][2];   // [qb][m]
#pragma unroll
        for (int qb = 0; qb < 4; ++qb) {
            union { unsigned int u[4]; bf16x8 v; } cv[2];
#pragma unroll
            for (int kvf = 0; kvf < 4; ++kvf) {
                const float p0 = fast_exp2(st[qb][kvf][0]);
                const float p1 = fast_exp2(st[qb][kvf][1]);
                const float p2 = fast_exp2(st[qb][kvf][2]);
                const float p3 = fast_exp2(st[qb][kvf][3]);
                cv[kvf >> 1].u[(kvf & 1) * 2 + 0] = cvt_pk_bf16(p0, p1);
                cv[kvf >> 1].u[(kvf & 1) * 2 + 1] = cvt_pk_bf16(p2, p3);
            }
            pf[qb][0] = cv[0].v;
            pf[qb][1] = cv[1].v;
        }

        // ---- O += P.V ; lsum += P.ones
        __builtin_amdgcn_s_setprio(1);
#pragma unroll
        for (int m = 0; m < 2; ++m) {
#pragma unroll
            for (int dblk = 0; dblk < 4; ++dblk) {
#pragma unroll
                for (int qb = 0; qb < 4; ++qb)
                    oacc[qb][dblk] =
                        __builtin_amdgcn_mfma_f32_16x16x32_bf16(pf[qb][m], vfm[m][dblk], oacc[qb][dblk], 0, 0, 0);
            }
#pragma unroll
            for (int qb = 0; qb < 4; ++qb)
                lacc[qb] =
                    __builtin_amdgcn_mfma_f32_16x16x32_bf16(pf[qb][m], ones, lacc[qb], 0, 0, 0);
        }
        __builtin_amdgcn_s_setprio(0);
    }

    // ---- epilogue: lacc already holds row sums in oacc's row layout -> just divide
#pragma unroll
    for (int qb = 0; qb < 4; ++qb) {
        float linv[4];
#pragma unroll
        for (int r = 0; r < 4; ++r) linv[r] = fast_rcp(lacc[qb][r]);
#pragma unroll
        for (int dblk = 0; dblk < 4; ++dblk)
#pragma unroll
            for (int r = 0; r < 4; ++r)
                O[(size_t)(q0 + qb * 16 + quad * 4 + r) * D_DIM + dblk * 16 + lc] =
                    oacc[qb][dblk][r] * linv[r];
    }
}

extern "C" void kernel_launch(void* const* d_in, const int* in_sizes, int n_in,
                              void* d_out, int out_size, void* d_ws, size_t ws_size,
                              hipStream_t stream) {
    const float* Q = (const float*)d_in[0];
    const float* K = (const float*)d_in[1];
    const float* V = (const float*)d_in[2];
    float* O = (float*)d_out;
    (void)in_sizes; (void)n_in; (void)out_size; (void)d_ws; (void)ws_size;

    dim3 grid(BH, 8);   // x = bh (XCD locality), y = q tile (256 rows each)
    attn_fwd<<<grid, 256, 0, stream>>>(Q, K, V, O);
}

// Round 8
// 181.380 us; speedup vs baseline: 1.1267x; 1.1267x over previous
//
#include <hip/hip_runtime.h>
#include <cstdint>

// BatchInvariantAttention: B=4 H=16 S=2048 D=64, fp32 in/out, full softmax attention.
// v9 = v7's exact schedule (64 q rows/wave, 1 barrier/chunk, in-register P, MFMA
// row-sum, V-frags read INSIDE the m-loop and immediately consumed -- the 99us,
// 120-VGPR, spill-free structure) + v8's bank-minimal V slot swizzle:
//   element (d, kv) lives at  vb[d*64 + 4*((kv>>2) ^ (d&15)) + (kv&3)]
// which took SQ_LDS_BANK_CONFLICT 11.5M -> 3.1M. v8's V-frag HOIST is reverted:
// it added +32 live VGPRs over the exp phase and caused scratch spills
// (WRITE_SIZE 32.8->39.4MB, attn 99->115us). Pressure profile restored to v7's.

#define S_LEN 2048
#define D_DIM 64
#define BN 64
#define NCHUNK (S_LEN / BN)
#define BH 64

typedef __attribute__((ext_vector_type(8))) short bf16x8;
typedef __attribute__((ext_vector_type(4))) float f32x4;
typedef __attribute__((ext_vector_type(2))) unsigned int u32x2;

static __device__ __forceinline__ float fast_exp2(float x) {
#if __has_builtin(__builtin_amdgcn_exp2f)
    return __builtin_amdgcn_exp2f(x);
#else
    float r;
    asm volatile("v_exp_f32 %0, %1" : "=v"(r) : "v"(x));
    return r;
#endif
}

static __device__ __forceinline__ float fast_rcp(float x) {
#if __has_builtin(__builtin_amdgcn_rcpf)
    return __builtin_amdgcn_rcpf(x);
#else
    return 1.0f / x;
#endif
}

// single-instruction packed cvt (RNE). dst.lo = bf16(a), dst.hi = bf16(b)
static __device__ __forceinline__ unsigned int cvt_pk_bf16(float a, float b) {
    unsigned int r;
    asm("v_cvt_pk_bf16_f32 %0, %1, %2" : "=v"(r) : "v"(a), "v"(b));
    return r;
}

__global__ __launch_bounds__(256, 2)
void attn_fwd(const float* __restrict__ Qg, const float* __restrict__ Kg,
              const float* __restrict__ Vg, float* __restrict__ Og) {
    const int bh   = blockIdx.x;   // 0..63 (fastest -> XCD = bh%8; same-bh blocks share XCD)
    const int tile = blockIdx.y;   // 0..7
    const int tid  = threadIdx.x;
    const int wave = tid >> 6;
    const int lane = tid & 63;
    const int quad = lane >> 4;
    const int lc   = lane & 15;

    const size_t base = (size_t)bh * S_LEN * D_DIM;
    const float* Q = Qg + base;
    const float* K = Kg + base;
    const float* V = Vg + base;
    float*       O = Og + base;

    const int q0 = tile * 256 + wave * 64;   // this wave's 64 q rows

    __shared__ __align__(16) short Kb[2][64 * 64];   // [kv][d], granule ^ (kv&7) swizzle
    __shared__ __align__(16) short Vt[2][64 * 64];   // [d][kv], slot = (kv>>2)^(d&15)
    // 32768 B total

    // ---- Q fragments (B-operand: n=lc=q, k slots = quad*8+j), scale = log2(e)/8 folded in
    const float QSCALE = 1.44269504088896f / 8.0f;
    bf16x8 qf[4][2];
#pragma unroll
    for (int qb = 0; qb < 4; ++qb)
#pragma unroll
        for (int dc = 0; dc < 2; ++dc) {
            const float* src = Q + (size_t)(q0 + qb * 16 + lc) * D_DIM + dc * 32 + quad * 8;
            f32x4 a = *(const f32x4*)src;
            f32x4 b = *(const f32x4*)(src + 4);
            union { unsigned int u[4]; bf16x8 v; } cvt;
            cvt.u[0] = cvt_pk_bf16(a[0] * QSCALE, a[1] * QSCALE);
            cvt.u[1] = cvt_pk_bf16(a[2] * QSCALE, a[3] * QSCALE);
            cvt.u[2] = cvt_pk_bf16(b[0] * QSCALE, b[1] * QSCALE);
            cvt.u[3] = cvt_pk_bf16(b[2] * QSCALE, b[3] * QSCALE);
            qf[qb][dc] = cvt.v;
        }

    // all-ones bf16 B-fragment for the row-sum MFMA
    bf16x8 ones;
    {
        union { unsigned int u[4]; bf16x8 v; } cv;
#pragma unroll
        for (int i = 0; i < 4; ++i) cv.u[i] = 0x3F803F80u;
        ones = cv.v;
    }

    f32x4 oacc[4][4];   // [qb][dblk]  O accumulators (C layout: row=q=quad*4+r, col=d=lc)
    f32x4 lacc[4];      // [qb]        row-sum accumulators (same row layout)
#pragma unroll
    for (int qb = 0; qb < 4; ++qb) {
        lacc[qb] = (f32x4){0.f, 0.f, 0.f, 0.f};
#pragma unroll
        for (int dblk = 0; dblk < 4; ++dblk)
            oacc[qb][dblk] = (f32x4){0.f, 0.f, 0.f, 0.f};
    }

    // staging addressing (each thread stages 4 K row-quarters + a 4x4 V micro-tile)
    const int krow = tid >> 4;           // 0..15
    const int kcol = (tid & 15) * 4;     // d offset 0,4,..,60
    const int gk   = kcol >> 3;          // 16B granule of kcol
    const int vkm  = (tid >> 4) * 4;     // kv micro-base for V transpose
    const int vu   = vkm >> 2;           // kv slot index (0..15)
    const float* kptr = K + (size_t)krow * D_DIM + kcol;
    const float* vptr = V + (size_t)vkm * D_DIM + kcol;

    // prologue: chunk 0 globals in flight
    f32x4 kreg[4], vreg[4];
#pragma unroll
    for (int i = 0; i < 4; ++i) kreg[i] = *(const f32x4*)(kptr + (size_t)i * 16 * D_DIM);
#pragma unroll
    for (int i = 0; i < 4; ++i) vreg[i] = *(const f32x4*)(vptr + (size_t)i * D_DIM);
    kptr += BN * D_DIM;
    vptr += BN * D_DIM;

#pragma unroll 1
    for (int ch = 0; ch < NCHUNK; ++ch) {
        short* kb = Kb[ch & 1];
        short* vb = Vt[ch & 1];

        // ---- publish this chunk (WAR-safe with 1 barrier: readers of buf[ch&1]
        // finished before the previous barrier)
#pragma unroll
        for (int i = 0; i < 4; ++i) {
            const int row = krow + i * 16;
            u32x2 w;
            w[0] = cvt_pk_bf16(kreg[i][0], kreg[i][1]);
            w[1] = cvt_pk_bf16(kreg[i][2], kreg[i][3]);
            *(u32x2*)(&kb[row * 64 + ((gk ^ (row & 7)) << 3) + (kcol & 7)]) = w;
        }
#pragma unroll
        for (int j = 0; j < 4; ++j) {   // 4x4 in-register transpose of V micro-tile
            const int d = kcol + j;
            u32x2 w;
            w[0] = cvt_pk_bf16(vreg[0][j], vreg[1][j]);   // kv = vkm+0, vkm+1
            w[1] = cvt_pk_bf16(vreg[2][j], vreg[3][j]);   // kv = vkm+2, vkm+3
            *(u32x2*)(&vb[d * 64 + 4 * (vu ^ (d & 15))]) = w;
        }

        // ---- prefetch next chunk's globals (in flight across barrier + compute)
        if (ch + 1 < NCHUNK) {
#pragma unroll
            for (int i = 0; i < 4; ++i) kreg[i] = *(const f32x4*)(kptr + (size_t)i * 16 * D_DIM);
#pragma unroll
            for (int i = 0; i < 4; ++i) vreg[i] = *(const f32x4*)(vptr + (size_t)i * D_DIM);
            kptr += BN * D_DIM;
            vptr += BN * D_DIM;
        }

        __syncthreads();   // tiles visible to all waves (one barrier per chunk)

        // ---- S^T = K_tile . Q^T : C frag lane holds q=lc, kv = kvf*16 + quad*4 + r
        f32x4 st[4][4];    // [qb][kvf]
        __builtin_amdgcn_s_setprio(1);
#pragma unroll
        for (int kvf = 0; kvf < 4; ++kvf) {
            const int krr = kvf * 16 + lc;
            const bf16x8 ka  = *(const bf16x8*)(&kb[krr * 64 + ((quad       ^ (lc & 7)) << 3)]);
            const bf16x8 kb2 = *(const bf16x8*)(&kb[krr * 64 + (((quad + 4) ^ (lc & 7)) << 3)]);
#pragma unroll
            for (int qb = 0; qb < 4; ++qb) {
                f32x4 c = {0.f, 0.f, 0.f, 0.f};
                c = __builtin_amdgcn_mfma_f32_16x16x32_bf16(ka,  qf[qb][0], c, 0, 0, 0);
                c = __builtin_amdgcn_mfma_f32_16x16x32_bf16(kb2, qf[qb][1], c, 0, 0, 0);
                st[qb][kvf] = c;
            }
        }
        __builtin_amdgcn_s_setprio(0);

        // ---- p = exp2(s); PV A-frags built IN REGISTERS (HW-proven layout).
        // Lane (q=lc, quad t) holds P[q][kv=16kvf+4t+r]. Slot j of pf[qb][m] is
        // st[qb][2m+(j>>2)][j&3]  ->  kv = 32m + 16(j>>2) + 4t + (j&3).
        bf16x8 pf[4][2];   // [qb][m]
#pragma unroll
        for (int qb = 0; qb < 4; ++qb) {
            union { unsigned int u[4]; bf16x8 v; } cv[2];
#pragma unroll
            for (int kvf = 0; kvf < 4; ++kvf) {
                const float p0 = fast_exp2(st[qb][kvf][0]);
                const float p1 = fast_exp2(st[qb][kvf][1]);
                const float p2 = fast_exp2(st[qb][kvf][2]);
                const float p3 = fast_exp2(st[qb][kvf][3]);
                cv[kvf >> 1].u[(kvf & 1) * 2 + 0] = cvt_pk_bf16(p0, p1);
                cv[kvf >> 1].u[(kvf & 1) * 2 + 1] = cvt_pk_bf16(p2, p3);
            }
            pf[qb][0] = cv[0].v;
            pf[qb][1] = cv[1].v;
        }

        // ---- O += P.V ; lsum += P.ones : V B-frag slot j = V[kv=32m+16(j>>2)+4t+(j&3)][d]
        //   q[0] <- slot (8m+quad)^(d&15), q[1] <- slot (8m+4+quad)^(d&15)
        // (reads INSIDE the m-loop, immediately consumed -- v7's pressure profile)
#pragma unroll
        for (int m = 0; m < 2; ++m) {
            bf16x8 vfm[4];
#pragma unroll
            for (int dblk = 0; dblk < 4; ++dblk) {
                const int d = dblk * 16 + lc;
                union { unsigned long long q[2]; bf16x8 v; } uv;
                uv.q[0] = *(const unsigned long long*)(&vb[d * 64 + 4 * ((8 * m + quad)     ^ (d & 15))]);
                uv.q[1] = *(const unsigned long long*)(&vb[d * 64 + 4 * ((8 * m + 4 + quad) ^ (d & 15))]);
                vfm[dblk] = uv.v;
            }
            __builtin_amdgcn_s_setprio(1);
#pragma unroll
            for (int dblk = 0; dblk < 4; ++dblk) {
#pragma unroll
                for (int qb = 0; qb < 4; ++qb)
                    oacc[qb][dblk] =
                        __builtin_amdgcn_mfma_f32_16x16x32_bf16(pf[qb][m], vfm[dblk], oacc[qb][dblk], 0, 0, 0);
            }
#pragma unroll
            for (int qb = 0; qb < 4; ++qb)
                lacc[qb] =
                    __builtin_amdgcn_mfma_f32_16x16x32_bf16(pf[qb][m], ones, lacc[qb], 0, 0, 0);
            __builtin_amdgcn_s_setprio(0);
        }
    }

    // ---- epilogue: lacc already holds row sums in oacc's row layout -> just divide
#pragma unroll
    for (int qb = 0; qb < 4; ++qb) {
        float linv[4];
#pragma unroll
        for (int r = 0; r < 4; ++r) linv[r] = fast_rcp(lacc[qb][r]);
#pragma unroll
        for (int dblk = 0; dblk < 4; ++dblk)
#pragma unroll
            for (int r = 0; r < 4; ++r)
                O[(size_t)(q0 + qb * 16 + quad * 4 + r) * D_DIM + dblk * 16 + lc] =
                    oacc[qb][dblk][r] * linv[r];
    }
}

extern "C" void kernel_launch(void* const* d_in, const int* in_sizes, int n_in,
                              void* d_out, int out_size, void* d_ws, size_t ws_size,
                              hipStream_t stream) {
    const float* Q = (const float*)d_in[0];
    const float* K = (const float*)d_in[1];
    const float* V = (const float*)d_in[2];
    float* O = (float*)d_out;
    (void)in_sizes; (void)n_in; (void)out_size; (void)d_ws; (void)ws_size;

    dim3 grid(BH, 8);   // x = bh (XCD locality), y = q tile (256 rows each)
    attn_fwd<<<grid, 256, 0, stream>>>(Q, K, V, O);
}